// Round 11
// baseline (202.634 us; speedup 1.0000x reference)
//
#include <hip/hip_runtime.h>
#include <stdint.h>

#define S_ 2048
#define H_ 16

typedef short s16x8 __attribute__((ext_vector_type(8)));
typedef float f32x4 __attribute__((ext_vector_type(4)));
typedef float f32x16 __attribute__((ext_vector_type(16)));

__device__ __forceinline__ ushort f2bf(float f) {
    union { float f; uint32_t u; } v; v.f = f;
    uint32_t r = v.u + 0x7fffu + ((v.u >> 16) & 1u);
    return (ushort)(r >> 16);
}
__device__ __forceinline__ uint32_t cvtpk(float a, float b) {
    uint32_t r;
    asm("v_cvt_pk_bf16_f32 %0, %1, %2" : "=v"(r) : "v"(a), "v"(b));
    return r;
}
__device__ __forceinline__ void plswap(uint32_t& a, uint32_t& b) {
    auto r = __builtin_amdgcn_permlane32_swap((int)a, (int)b, false, false);
    a = (uint32_t)r[0];
    b = (uint32_t)r[1];
}
__device__ __forceinline__ float xmax32(float x) {
    uint32_t a = __float_as_uint(x), b = a;
    plswap(a, b);
    return fmaxf(__uint_as_float(a), __uint_as_float(b));
}
__device__ __forceinline__ float xadd32(float x) {
    uint32_t a = __float_as_uint(x), b = a;
    plswap(a, b);
    return __uint_as_float(a) + __uint_as_float(b);
}
__device__ __forceinline__ float exp2_fast(float x) {
    float r;
    asm("v_exp_f32 %0, %1" : "=v"(r) : "v"(x));
    return r;
}

// async global->LDS, 16B per lane. LDS dest = wave-uniform base + lane*16.
__device__ __forceinline__ void gld16(ushort* lds, const ushort* g) {
    auto* gp = reinterpret_cast<uint32_t __attribute__((address_space(1)))*>(
        reinterpret_cast<uintptr_t>(g));
    auto* lp = reinterpret_cast<uint32_t __attribute__((address_space(3)))*>(
        reinterpret_cast<uintptr_t>(lds));
    __builtin_amdgcn_global_load_lds(gp, lp, 16, 0, 0);
}

// ---- X fp32 -> bf16 ----
__global__ void cast_bf16(const float* __restrict__ src, ushort* __restrict__ dst) {
    size_t i = ((size_t)blockIdx.x * 256 + threadIdx.x) * 8;
    float4 x = *(const float4*)(src + i);
    float4 y = *(const float4*)(src + i + 4);
    s16x8 r;
    r[0] = (short)f2bf(x.x); r[1] = (short)f2bf(x.y);
    r[2] = (short)f2bf(x.z); r[3] = (short)f2bf(x.w);
    r[4] = (short)f2bf(y.x); r[5] = (short)f2bf(y.y);
    r[6] = (short)f2bf(y.z); r[7] = (short)f2bf(y.w);
    *(s16x8*)(dst + i) = r;
}

// ---- weight prep: dst[n*1024+k] = bf16(src[k*1024+n]) ----
__global__ void transpose_k4(const float* __restrict__ s0, const float* __restrict__ s1,
                             const float* __restrict__ s2, const float* __restrict__ s3,
                             ushort* __restrict__ d0, ushort* __restrict__ d1,
                             ushort* __restrict__ d2, ushort* __restrict__ d3) {
    const int z = blockIdx.z;
    const float* src = (z == 0) ? s0 : (z == 1) ? s1 : (z == 2) ? s2 : s3;
    ushort* dst      = (z == 0) ? d0 : (z == 1) ? d1 : (z == 2) ? d2 : d3;
    __shared__ ushort t[32][33];
    int bx = blockIdx.x * 32, by = blockIdx.y * 32;
    int x = threadIdx.x;
    for (int y = threadIdx.y; y < 32; y += 8)
        t[y][x] = f2bf(src[(size_t)(by + y) * 1024 + bx + x]);
    __syncthreads();
    for (int y = threadIdx.y; y < 32; y += 8)
        dst[(size_t)(bx + y) * 1024 + by + x] = t[x][y];
}

// ---------------- GEMM: C[m,n] = A[M,K] @ Bt[N,K]^T + bias(fp32) ------------
// R10-verbatim (BK=64, chunk-XOR swizzle, XCD swizzle; proven absmax 4.88e-4).
#define MFMA16(a, b, c) __builtin_amdgcn_mfma_f32_16x16x32_bf16(a, b, c, 0, 0, 0)

__global__ __launch_bounds__(256, 4) void gemm_bt(
        const ushort* __restrict__ A,
        const ushort* __restrict__ Bt0, const ushort* __restrict__ Bt1,
        const ushort* __restrict__ Bt2,
        const float* __restrict__ bi0, const float* __restrict__ bi1,
        const float* __restrict__ bi2,
        void* __restrict__ o0, void* __restrict__ o1, void* __restrict__ o2,
        int mode0) {
    const int z = blockIdx.z;
    const ushort* Bt  = (z == 0) ? Bt0 : (z == 1) ? Bt1 : Bt2;
    const float* bia  = (z == 0) ? bi0 : (z == 1) ? bi1 : bi2;
    void* out         = (z == 0) ? o0  : (z == 1) ? o1  : o2;
    const int mode = mode0 + z;

    __shared__ __align__(16) ushort Asm[128 * 64];  // 16KB
    __shared__ __align__(16) ushort Bsm[128 * 64];  // 16KB

    const int t = threadIdx.x;
    const int lane = t & 63, w = t >> 6;
    const int wm = w >> 1, wn = w & 1;
    const int quad = lane >> 4, l16 = lane & 15;

    const int bid = blockIdx.y * 8 + blockIdx.x;
    const int swz = (bid & 7) * 32 + (bid >> 3);
    const int m0 = (swz >> 3) * 128, n0 = (swz & 7) * 128;
    const int K = 1024;

    const f32x4 FZ = {0.f, 0.f, 0.f, 0.f};
    f32x4 acc[4][4];
#pragma unroll
    for (int i = 0; i < 4; i++)
#pragma unroll
        for (int j = 0; j < 4; j++) acc[i][j] = FZ;

    const int rr = t >> 3;
    const int sc = (t & 7) ^ (rr & 7);
    const ushort* Ap = A  + (size_t)(m0 + rr) * K + sc * 8;
    const ushort* Bp = Bt + (size_t)(n0 + rr) * K + sc * 8;
    ushort* AsmW = Asm + w * 512;
    ushort* BsmW = Bsm + w * 512;

    const int fx = l16 & 7;

    for (int kt = 0; kt < 16; ++kt) {
        __syncthreads();
        const int o = kt * 64;
#pragma unroll
        for (int g = 0; g < 4; g++) {
            gld16(AsmW + g * 2048, Ap + (size_t)(g * 32) * K + o);
            gld16(BsmW + g * 2048, Bp + (size_t)(g * 32) * K + o);
        }
        __syncthreads();

#pragma unroll
        for (int ks = 0; ks < 2; ks++) {
            const int ck = (((ks << 2) | quad) ^ fx) * 8;
            s16x8 a[4], b[4];
#pragma unroll
            for (int i = 0; i < 4; i++)
                a[i] = *(const s16x8*)&Asm[(wm * 64 + i * 16 + l16) * 64 + ck];
#pragma unroll
            for (int j = 0; j < 4; j++)
                b[j] = *(const s16x8*)&Bsm[(wn * 64 + j * 16 + l16) * 64 + ck];
#pragma unroll
            for (int i = 0; i < 4; i++)
#pragma unroll
                for (int j = 0; j < 4; j++)
                    acc[i][j] = MFMA16(a[i], b[j], acc[i][j]);
        }
    }

    if (mode == 3) {
        ushort* T = Asm;
        const int b_ = m0 >> 11;
        const int s_base = m0 & 2047;
        __syncthreads();
#pragma unroll
        for (int half = 0; half < 2; ++half) {
            if (wn == half) {
#pragma unroll
                for (int j = 0; j < 4; j++) {
                    int nl = j * 16 + l16;
                    float bv = bia[n0 + half * 64 + nl];
#pragma unroll
                    for (int i = 0; i < 4; i++) {
#pragma unroll
                        for (int r = 0; r < 4; r++) {
                            int ml = wm * 64 + i * 16 + quad * 4 + r;
                            T[nl * 128 + (ml ^ ((nl & 15) << 3))] = f2bf(acc[i][j][r] + bv);
                        }
                    }
                }
            }
            __syncthreads();
            {
                int row = t >> 2, cg = (t & 3) * 32;
                int ng = n0 + half * 64 + row;
                int h = ng >> 6, d = ng & 63;
                ushort* op = (ushort*)out + ((size_t)((b_ * 16 + h) * 64 + d)) * 2048 + s_base + cg;
#pragma unroll
                for (int c = 0; c < 4; c++) {
                    int col = (cg + c * 8) ^ ((row & 15) << 3);
                    *(s16x8*)(op + c * 8) = *(const s16x8*)(T + row * 128 + col);
                }
            }
            __syncthreads();
        }
        return;
    }

#pragma unroll
    for (int j = 0; j < 4; j++) {
        int n = n0 + wn * 64 + j * 16 + l16;
        float bv = bia[n];
#pragma unroll
        for (int i = 0; i < 4; i++) {
#pragma unroll
            for (int r = 0; r < 4; r++) {
                int m = m0 + wm * 64 + i * 16 + quad * 4 + r;
                float v = acc[i][j][r] + bv;
                if (mode == 0) {
                    ((float*)out)[(size_t)m * 1024 + n] = v;
                } else {
                    int b_ = m >> 11, s = m & 2047;
                    int h = n >> 6, d = n & 63;
                    if (mode == 1)  // 0.125*log2(e): attn softmax runs in exp2 domain
                        ((ushort*)out)[((size_t)(b_ * 16 + h) * 2048 + s) * 64 + d] = f2bf(v * 0.18033688011112042f);
                    else
                        ((ushort*)out)[((size_t)(b_ * 16 + h) * 2048 + s) * 64 + d] = f2bf(v);
                }
            }
        }
    }
}

// ---------------- MFMA flash attention: counted-vmcnt 3-buffer pipeline ------
// R10 math verbatim (defer-max + setprio + cvt_pk/permlane pack, exp2 domain).
// NEW (T3/T4): replace {issue; compute; __syncthreads-drain} with 3-buffer
// rotation: per iter [vmcnt(4) -> s_barrier -> issue tile t+2 -> compute t ->
// lgkmcnt(0)]. Newest 4 loads stay in flight across the barrier (2-tile
// latency window). Safety proof (wave skew <= 1 iter): writer of tile t+2
// touches buf[(t+2)%3]; concurrent readers hold buf[t%3], buf[(t-1)%3] —
// distinct mod 3. lgkmcnt(0) at loop end: own ds_reads of buf[t%3] complete
// before it is overwritten (tile t+3, next iter). Stages guarded kt<30 and
// vmcnt(0) on last iter: no gld16 outstanding or targeting obuf overlay
// (buf0/1) during epilogue; final compute reads buf2 only.
#define MFMA32(a, b, c) __builtin_amdgcn_mfma_f32_32x32x16_bf16(a, b, c, 0, 0, 0)

__global__ __launch_bounds__(256, 2) void attn(const ushort* __restrict__ q_ws,
                                               const ushort* __restrict__ k_ws,
                                               const ushort* __restrict__ vt_ws,
                                               ushort* __restrict__ ctx) {
    // buffer b at SM + b*8192 (K: 4096 ushorts, V: +4096). 48KB total.
    __shared__ __align__(16) ushort SM[3 * 8192];

    const int t = threadIdx.x, lane = t & 63, w = t >> 6;
    const int l32 = lane & 31, hi = lane >> 5;

    const int bid = blockIdx.x;
    const int j_ = bid >> 3;
    const int bh = (bid & 7) + 8 * (j_ >> 4);
    const int q0 = (j_ & 15) * 128 + w * 32;

    const ushort* Qg = q_ws + (size_t)bh * S_ * 64;
    const ushort* Kg = k_ws + (size_t)bh * S_ * 64;
    const ushort* Vg = vt_ws + (size_t)bh * 64 * S_;

    s16x8 qf[4];
#pragma unroll
    for (int dc = 0; dc < 4; dc++)
        qf[dc] = *(const s16x8*)&Qg[(size_t)(q0 + l32) * 64 + dc * 16 + hi * 8];

    const int sr = t >> 3;
    const int sc = (t & 7) ^ (sr & 7);
    const ushort* kS = Kg + sr * 64 + sc * 8;
    const ushort* vS = Vg + (size_t)sr * 2048 + sc * 8;

    // stage tile (kt) into buffer (bufidx): K rows 0-31 / 32-63, V rows 0-31 / 32-63
#define STG(bufidx, kt) do {                                        \
    ushort* dK = SM + (bufidx) * 8192 + w * 512;                    \
    const ushort* kn = kS + (size_t)(kt) * 4096;                    \
    const ushort* vn = vS + (kt) * 64;                              \
    gld16(dK,               kn);                                    \
    gld16(dK + 2048,        kn + 2048);                             \
    gld16(dK + 4096,        vn);                                    \
    gld16(dK + 4096 + 2048, vn + (size_t)32 * 2048);                \
} while (0)

    int fo[4];
#pragma unroll
    for (int c = 0; c < 4; c++)
        fo[c] = l32 * 64 + ((((c << 1) | hi) ^ (l32 & 7)) << 3);

    const f32x16 Z16 = {0.f,0.f,0.f,0.f,0.f,0.f,0.f,0.f,0.f,0.f,0.f,0.f,0.f,0.f,0.f,0.f};
    f32x16 o0 = Z16, o1 = Z16;
    float m_run = -1e30f, l_run = 0.f;

    STG(0, 0);
    STG(1, 1);

    int cb = 0, nb = 2;
    for (int kt = 0; kt < S_ / 64; ++kt) {
        if (kt == S_ / 64 - 1) asm volatile("s_waitcnt vmcnt(0)" ::: "memory");
        else                   asm volatile("s_waitcnt vmcnt(4)" ::: "memory");
        __builtin_amdgcn_s_barrier();
        __builtin_amdgcn_sched_barrier(0);
        if (kt < S_ / 64 - 2) STG(nb, kt + 2);

        const ushort* KB = SM + cb * 8192;
        const ushort* VB = KB + 4096;

        f32x16 s0 = Z16, s1 = Z16;
        __builtin_amdgcn_s_setprio(1);
#pragma unroll
        for (int dc = 0; dc < 4; dc++) {
            s16x8 k0 = *(const s16x8*)(KB + fo[dc]);
            s16x8 k1 = *(const s16x8*)(KB + 2048 + fo[dc]);
            s0 = MFMA32(k0, qf[dc], s0);
            s1 = MFMA32(k1, qf[dc], s1);
        }
        __builtin_amdgcn_s_setprio(0);

        float m0 = fmaxf(s0[0], s1[0]), m1 = fmaxf(s0[1], s1[1]);
        float m2 = fmaxf(s0[2], s1[2]), m3 = fmaxf(s0[3], s1[3]);
#pragma unroll
        for (int r = 4; r < 16; r += 4) {
            m0 = fmaxf(m0, fmaxf(s0[r],     s1[r]));
            m1 = fmaxf(m1, fmaxf(s0[r + 1], s1[r + 1]));
            m2 = fmaxf(m2, fmaxf(s0[r + 2], s1[r + 2]));
            m3 = fmaxf(m3, fmaxf(s0[r + 3], s1[r + 3]));
        }
        float mx = fmaxf(fmaxf(m0, m1), fmaxf(m2, m3));
        mx = xmax32(mx);

        // T13 defer-max: rescale only when the tile max meaningfully grows
        if (__any(mx > m_run + 8.f)) {
            float mnew = fmaxf(m_run, mx);
            float alpha = exp2_fast(m_run - mnew);
            m_run = mnew;
            l_run *= alpha;
#pragma unroll
            for (int r = 0; r < 16; r++) { o0[r] *= alpha; o1[r] *= alpha; }
        }

        float ra = 0.f, rb = 0.f;
#pragma unroll
        for (int r = 0; r < 16; r++) {
            s0[r] = exp2_fast(s0[r] - m_run); ra += s0[r];
            s1[r] = exp2_fast(s1[r] - m_run); rb += s1[r];
        }
        l_run += xadd32(ra + rb);

#pragma unroll
        for (int ks = 0; ks < 2; ks++) {
            const f32x16& p = ks ? s1 : s0;
            uint32_t u0 = cvtpk(p[0], p[1]),   u2 = cvtpk(p[4], p[5]);
            plswap(u0, u2);
            uint32_t u1 = cvtpk(p[2], p[3]),   u3 = cvtpk(p[6], p[7]);
            plswap(u1, u3);
            uint32_t w0 = cvtpk(p[8], p[9]),   w2 = cvtpk(p[12], p[13]);
            plswap(w0, w2);
            uint32_t w1 = cvtpk(p[10], p[11]), w3 = cvtpk(p[14], p[15]);
            plswap(w1, w3);
            union { uint32_t u[4]; s16x8 h; } F0, F1;
            F0.u[0] = u0; F0.u[1] = u1; F0.u[2] = u2; F0.u[3] = u3;
            F1.u[0] = w0; F1.u[1] = w1; F1.u[2] = w2; F1.u[3] = w3;

            const int kc0 = ks * 2, kc1 = ks * 2 + 1;
            s16x8 v00 = *(const s16x8*)(VB + fo[kc0]);
            s16x8 v01 = *(const s16x8*)(VB + 2048 + fo[kc0]);
            s16x8 v10 = *(const s16x8*)(VB + fo[kc1]);
            s16x8 v11 = *(const s16x8*)(VB + 2048 + fo[kc1]);
            __builtin_amdgcn_s_setprio(1);
            o0 = MFMA32(v00, F0.h, o0); o1 = MFMA32(v01, F0.h, o1);
            o0 = MFMA32(v10, F1.h, o0); o1 = MFMA32(v11, F1.h, o1);
            __builtin_amdgcn_s_setprio(0);
        }

        // own ds_reads of buf[cb] drained before tile kt+3 overwrites it
        asm volatile("s_waitcnt lgkmcnt(0)" ::: "memory");
        cb = (cb == 2) ? 0 : cb + 1;
        nb = (nb == 2) ? 0 : nb + 1;
    }
#undef STG

    // epilogue: obuf overlays SM[0 .. 9216) (buf0 + part of buf1).
    // Safe: all gld16 drained (vmcnt(0) before barrier_31); slowest wave's
    // compute(31) reads buf2 = SM[16384..); obuf region is wave-private.
    ushort* obuf = SM;  // [4][32][72]: ((w*32+l32)*72 + idx)
    float inv = 1.0f / l_run;
    const int ob = (w * 32 + l32) * 72;
#pragma unroll
    for (int r = 0; r < 16; r++) {
        int d0 = (r & 3) + 8 * (r >> 2) + 4 * hi;
        obuf[ob + d0]      = f2bf(o0[r] * inv);
        obuf[ob + 32 + d0] = f2bf(o1[r] * inv);
    }
    asm volatile("s_waitcnt lgkmcnt(0)" ::: "memory");
    __builtin_amdgcn_sched_barrier(0);
    int b_ = bh >> 4, h = bh & 15;
    ushort* gp = ctx + ((size_t)(b_ * 2048 + q0 + l32)) * 1024 + h * 64 + hi * 32;
#pragma unroll
    for (int c = 0; c < 4; c++)
        *(s16x8*)(gp + c * 8) = *(const s16x8*)&obuf[ob + hi * 32 + c * 8];
}

extern "C" void kernel_launch(void* const* d_in, const int* in_sizes, int n_in,
                              void* d_out, int out_size, void* d_ws, size_t ws_size,
                              hipStream_t stream) {
    const float* X  = (const float*)d_in[0];
    const float* Wq = (const float*)d_in[1];
    const float* bq = (const float*)d_in[2];
    const float* Wk = (const float*)d_in[3];
    const float* bk = (const float*)d_in[4];
    const float* Wv = (const float*)d_in[5];
    const float* bv = (const float*)d_in[6];
    const float* Wo = (const float*)d_in[7];
    const float* bo = (const float*)d_in[8];
    float* out = (float*)d_out;

    // ws (MiB): wtq@0(2) wtk@2(2) wtv@4(2) wto@6(2) qws@8(8) kws@16(8)
    // ctx@24(8) = 32 MiB. d_out hosts V^T bf16 @0 (8 MiB) + Xbf16 @8MiB (8 MiB):
    // both dead before the final GEMM overwrites d_out. (attn's tail prefetch
    // may read a few KB past kws into ctx: allocated, unused — harmless.)
    char* ws = (char*)d_ws;
    ushort* wtq  = (ushort*)(ws);
    ushort* wtk  = (ushort*)(ws + ((size_t)2 << 20));
    ushort* wtv  = (ushort*)(ws + ((size_t)4 << 20));
    ushort* wto  = (ushort*)(ws + ((size_t)6 << 20));
    ushort* qws  = (ushort*)(ws + ((size_t)8 << 20));
    ushort* kws  = (ushort*)(ws + ((size_t)16 << 20));
    ushort* ctx  = (ushort*)(ws + ((size_t)24 << 20));
    ushort* vtws = (ushort*)d_out;
    ushort* xbf  = (ushort*)d_out + ((size_t)4 << 20);  // +8 MiB

    transpose_k4<<<dim3(32, 32, 4), dim3(32, 8), 0, stream>>>(Wq, Wk, Wv, Wo,
                                                              wtq, wtk, wtv, wto);
    cast_bf16<<<2048, 256, 0, stream>>>(X, xbf);

    // fused QKV projection (modes 1/2/3)
    gemm_bt<<<dim3(8, 32, 3), 256, 0, stream>>>(xbf, wtq, wtk, wtv, bq, bk, bv,
                                                qws, kws, vtws, 1);

    attn<<<dim3(512), 256, 0, stream>>>(qws, kws, vtws, ctx);

    // output projection (mode 0)
    gemm_bt<<<dim3(8, 32, 1), 256, 0, stream>>>(ctx, wto, wto, wto, bo, bo, bo,
                                                out, out, out, 0);
}

// Round 12
// 197.789 us; speedup vs baseline: 1.0245x; 1.0245x over previous
//
#include <hip/hip_runtime.h>
#include <stdint.h>

#define S_ 2048
#define H_ 16

typedef short s16x8 __attribute__((ext_vector_type(8)));
typedef float f32x4 __attribute__((ext_vector_type(4)));
typedef float f32x16 __attribute__((ext_vector_type(16)));

__device__ __forceinline__ ushort f2bf(float f) {
    union { float f; uint32_t u; } v; v.f = f;
    uint32_t r = v.u + 0x7fffu + ((v.u >> 16) & 1u);
    return (ushort)(r >> 16);
}
__device__ __forceinline__ uint32_t cvtpk(float a, float b) {
    uint32_t r;
    asm("v_cvt_pk_bf16_f32 %0, %1, %2" : "=v"(r) : "v"(a), "v"(b));
    return r;
}
__device__ __forceinline__ void plswap(uint32_t& a, uint32_t& b) {
    auto r = __builtin_amdgcn_permlane32_swap((int)a, (int)b, false, false);
    a = (uint32_t)r[0];
    b = (uint32_t)r[1];
}
__device__ __forceinline__ float xmax32(float x) {
    uint32_t a = __float_as_uint(x), b = a;
    plswap(a, b);
    return fmaxf(__uint_as_float(a), __uint_as_float(b));
}
__device__ __forceinline__ float xadd32(float x) {
    uint32_t a = __float_as_uint(x), b = a;
    plswap(a, b);
    return __uint_as_float(a) + __uint_as_float(b);
}
__device__ __forceinline__ float exp2_fast(float x) {
    float r;
    asm("v_exp_f32 %0, %1" : "=v"(r) : "v"(x));
    return r;
}

// async global->LDS, 16B per lane. LDS dest = wave-uniform base + lane*16.
__device__ __forceinline__ void gld16(ushort* lds, const ushort* g) {
    auto* gp = reinterpret_cast<uint32_t __attribute__((address_space(1)))*>(
        reinterpret_cast<uintptr_t>(g));
    auto* lp = reinterpret_cast<uint32_t __attribute__((address_space(3)))*>(
        reinterpret_cast<uintptr_t>(lds));
    __builtin_amdgcn_global_load_lds(gp, lp, 16, 0, 0);
}

// ---- prep: 4 weight transposes (z<4) + X fp32->bf16 cast (z=4,5), one launch ----
__global__ void prep(const float* __restrict__ s0, const float* __restrict__ s1,
                     const float* __restrict__ s2, const float* __restrict__ s3,
                     const float* __restrict__ X,
                     ushort* __restrict__ d0, ushort* __restrict__ d1,
                     ushort* __restrict__ d2, ushort* __restrict__ d3,
                     ushort* __restrict__ xdst) {
    const int z = blockIdx.z;
    if (z < 4) {
        const float* src = (z == 0) ? s0 : (z == 1) ? s1 : (z == 2) ? s2 : s3;
        ushort* dst      = (z == 0) ? d0 : (z == 1) ? d1 : (z == 2) ? d2 : d3;
        __shared__ ushort t[32][33];
        int bx = blockIdx.x * 32, by = blockIdx.y * 32;
        int x = threadIdx.x;
        for (int y = threadIdx.y; y < 32; y += 8)
            t[y][x] = f2bf(src[(size_t)(by + y) * 1024 + bx + x]);
        __syncthreads();
        for (int y = threadIdx.y; y < 32; y += 8)
            dst[(size_t)(bx + y) * 1024 + by + x] = t[x][y];
    } else {
        // cast: 2 z-slices x 1024 blocks x 256 threads x 8 elems = 4M = B*S*D_IN
        int bl = (z - 4) * 1024 + blockIdx.y * 32 + blockIdx.x;
        int tl = threadIdx.y * 32 + threadIdx.x;
        size_t i = ((size_t)bl * 256 + tl) * 8;
        float4 x = *(const float4*)(X + i);
        float4 y = *(const float4*)(X + i + 4);
        s16x8 r;
        r[0] = (short)f2bf(x.x); r[1] = (short)f2bf(x.y);
        r[2] = (short)f2bf(x.z); r[3] = (short)f2bf(x.w);
        r[4] = (short)f2bf(y.x); r[5] = (short)f2bf(y.y);
        r[6] = (short)f2bf(y.z); r[7] = (short)f2bf(y.w);
        *(s16x8*)(xdst + i) = r;
    }
}

// ---------------- GEMM: C[m,n] = A[M,K] @ Bt[N,K]^T + bias(fp32) ------------
// NEW (T3/T4, R11-proven rotation ported): BK=32, 3-buffer counted-vmcnt
// pipeline. Per iter: vmcnt(4) [own tile-t loads landed] -> s_barrier [all
// waves' -> tile t complete in LDS] -> STG(t+2 -> buf (t+2)%3) -> 16 MFMA
// from buf t%3 -> lgkmcnt(0) [own reads done before buf reuse]. Mod-3
// separation: writer(t+2) vs readers(t, t-1) distinct. LDS 48KB -> 3 blk/CU.
// Bank plan (64B rows): chunk-XOR c^=(row>>1)&3 both sides -> 2-way reads
// (free, m136). FLOP order identical to R10 -> bit-identical output.
// mode 0: fp32 out[m*1024+n]
// mode 1: Q bf16 out[((b*16+h)*2048+s)*64+d] = v * 0.125*log2(e)  (exp2 domain)
// mode 2: K bf16 same layout
// mode 3: Vt bf16 out[((b*16+h)*64+d)*2048+s] = v (LDS transpose, coalesced)
#define MFMA16(a, b, c) __builtin_amdgcn_mfma_f32_16x16x32_bf16(a, b, c, 0, 0, 0)

__global__ __launch_bounds__(256, 3) void gemm_bt(
        const ushort* __restrict__ A,
        const ushort* __restrict__ Bt0, const ushort* __restrict__ Bt1,
        const ushort* __restrict__ Bt2,
        const float* __restrict__ bi0, const float* __restrict__ bi1,
        const float* __restrict__ bi2,
        void* __restrict__ o0, void* __restrict__ o1, void* __restrict__ o2,
        int mode0) {
    const int z = blockIdx.z;
    const ushort* Bt  = (z == 0) ? Bt0 : (z == 1) ? Bt1 : Bt2;
    const float* bia  = (z == 0) ? bi0 : (z == 1) ? bi1 : bi2;
    void* out         = (z == 0) ? o0  : (z == 1) ? o1  : o2;
    const int mode = mode0 + z;

    // buffer b at SM + b*8192: A tile 4096 ushorts, B tile +4096. 48KB total.
    __shared__ __align__(16) ushort SM[3 * 8192];

    const int t = threadIdx.x;
    const int lane = t & 63, w = t >> 6;
    const int wm = w >> 1, wn = w & 1;
    const int quad = lane >> 4, l16 = lane & 15;

    const int bid = blockIdx.y * 8 + blockIdx.x;
    const int swz = (bid & 7) * 32 + (bid >> 3);
    const int m0 = (swz >> 3) * 128, n0 = (swz & 7) * 128;
    const int K = 1024;

    const f32x4 FZ = {0.f, 0.f, 0.f, 0.f};
    f32x4 acc[4][4];
#pragma unroll
    for (int i = 0; i < 4; i++)
#pragma unroll
        for (int j = 0; j < 4; j++) acc[i][j] = FZ;

    // staging: slot t -> row t>>2 (0..63), chunkpos t&3; slot t+256 -> row 64+.
    // source chunk = (t&3) ^ ((row>>1)&3); (64+row)>>1 == row>>1 (mod 4).
    const int rr = t >> 2;
    const int sc = (t & 3) ^ ((t >> 3) & 3);
    const ushort* Ap = A  + (size_t)(m0 + rr) * K + sc * 8;
    const ushort* Bp = Bt + (size_t)(n0 + rr) * K + sc * 8;

#define STG(bufidx, kt) do {                                        \
    ushort* dA = SM + (bufidx) * 8192 + w * 512;                    \
    const int _o = (kt) * 32;                                       \
    gld16(dA,               Ap + _o);                               \
    gld16(dA + 2048,        Ap + (size_t)64 * K + _o);              \
    gld16(dA + 4096,        Bp + _o);                               \
    gld16(dA + 4096 + 2048, Bp + (size_t)64 * K + _o);              \
} while (0)

    const int fx2 = (l16 >> 1) & 3;
    const int ck = (quad ^ fx2) * 8;

    STG(0, 0);
    STG(1, 1);

    int cb = 0, nb = 2;
    for (int kt = 0; kt < 32; ++kt) {
        if (kt == 31) asm volatile("s_waitcnt vmcnt(0)" ::: "memory");
        else          asm volatile("s_waitcnt vmcnt(4)" ::: "memory");
        __builtin_amdgcn_s_barrier();
        __builtin_amdgcn_sched_barrier(0);
        if (kt < 30) STG(nb, kt + 2);

        const ushort* Ab = SM + cb * 8192;
        const ushort* Bb = Ab + 4096;

        s16x8 a[4], b[4];
#pragma unroll
        for (int i = 0; i < 4; i++)
            a[i] = *(const s16x8*)&Ab[(wm * 64 + i * 16 + l16) * 32 + ck];
#pragma unroll
        for (int j = 0; j < 4; j++)
            b[j] = *(const s16x8*)&Bb[(wn * 64 + j * 16 + l16) * 32 + ck];
        __builtin_amdgcn_s_setprio(1);
#pragma unroll
        for (int i = 0; i < 4; i++)
#pragma unroll
            for (int j = 0; j < 4; j++)
                acc[i][j] = MFMA16(a[i], b[j], acc[i][j]);
        __builtin_amdgcn_s_setprio(0);

        asm volatile("s_waitcnt lgkmcnt(0)" ::: "memory");
        cb = (cb == 2) ? 0 : cb + 1;
        nb = (nb == 2) ? 0 : nb + 1;
    }
#undef STG

    if (mode == 3) {
        // V^T epilogue: transpose 128x128 tile through LDS (XOR-swizzled),
        // then coalesced 16B row stores. T = SM[0..8192): all gld16 drained
        // (vmcnt(0) @ kt=31), reads of buf0/1 done (lgkm + barrier below).
        ushort* T = SM;
        const int b_ = m0 >> 11;
        const int s_base = m0 & 2047;
        __syncthreads();
#pragma unroll
        for (int half = 0; half < 2; ++half) {
            if (wn == half) {
#pragma unroll
                for (int j = 0; j < 4; j++) {
                    int nl = j * 16 + l16;
                    float bv = bia[n0 + half * 64 + nl];
#pragma unroll
                    for (int i = 0; i < 4; i++) {
#pragma unroll
                        for (int r = 0; r < 4; r++) {
                            int ml = wm * 64 + i * 16 + quad * 4 + r;
                            T[nl * 128 + (ml ^ ((nl & 15) << 3))] = f2bf(acc[i][j][r] + bv);
                        }
                    }
                }
            }
            __syncthreads();
            {
                int row = t >> 2, cg = (t & 3) * 32;
                int ng = n0 + half * 64 + row;
                int h = ng >> 6, d = ng & 63;
                ushort* op = (ushort*)out + ((size_t)((b_ * 16 + h) * 64 + d)) * 2048 + s_base + cg;
#pragma unroll
                for (int c = 0; c < 4; c++) {
                    int col = (cg + c * 8) ^ ((row & 15) << 3);
                    *(s16x8*)(op + c * 8) = *(const s16x8*)(T + row * 128 + col);
                }
            }
            __syncthreads();
        }
        return;
    }

#pragma unroll
    for (int j = 0; j < 4; j++) {
        int n = n0 + wn * 64 + j * 16 + l16;
        float bv = bia[n];
#pragma unroll
        for (int i = 0; i < 4; i++) {
#pragma unroll
            for (int r = 0; r < 4; r++) {
                int m = m0 + wm * 64 + i * 16 + quad * 4 + r;
                float v = acc[i][j][r] + bv;
                if (mode == 0) {
                    ((float*)out)[(size_t)m * 1024 + n] = v;
                } else {
                    int b_ = m >> 11, s = m & 2047;
                    int h = n >> 6, d = n & 63;
                    if (mode == 1)  // 0.125*log2(e): attn softmax runs in exp2 domain
                        ((ushort*)out)[((size_t)(b_ * 16 + h) * 2048 + s) * 64 + d] = f2bf(v * 0.18033688011112042f);
                    else
                        ((ushort*)out)[((size_t)(b_ * 16 + h) * 2048 + s) * 64 + d] = f2bf(v);
                }
            }
        }
    }
}

// ---------------- MFMA flash attention: counted-vmcnt 3-buffer pipeline ------
// R11-verbatim (passed, 57.4us, absmax 4.88e-4).
#define MFMA32(a, b, c) __builtin_amdgcn_mfma_f32_32x32x16_bf16(a, b, c, 0, 0, 0)

__global__ __launch_bounds__(256, 2) void attn(const ushort* __restrict__ q_ws,
                                               const ushort* __restrict__ k_ws,
                                               const ushort* __restrict__ vt_ws,
                                               ushort* __restrict__ ctx) {
    __shared__ __align__(16) ushort SM[3 * 8192];

    const int t = threadIdx.x, lane = t & 63, w = t >> 6;
    const int l32 = lane & 31, hi = lane >> 5;

    const int bid = blockIdx.x;
    const int j_ = bid >> 3;
    const int bh = (bid & 7) + 8 * (j_ >> 4);
    const int q0 = (j_ & 15) * 128 + w * 32;

    const ushort* Qg = q_ws + (size_t)bh * S_ * 64;
    const ushort* Kg = k_ws + (size_t)bh * S_ * 64;
    const ushort* Vg = vt_ws + (size_t)bh * 64 * S_;

    s16x8 qf[4];
#pragma unroll
    for (int dc = 0; dc < 4; dc++)
        qf[dc] = *(const s16x8*)&Qg[(size_t)(q0 + l32) * 64 + dc * 16 + hi * 8];

    const int sr = t >> 3;
    const int sc = (t & 7) ^ (sr & 7);
    const ushort* kS = Kg + sr * 64 + sc * 8;
    const ushort* vS = Vg + (size_t)sr * 2048 + sc * 8;

#define STG(bufidx, kt) do {                                        \
    ushort* dK = SM + (bufidx) * 8192 + w * 512;                    \
    const ushort* kn = kS + (size_t)(kt) * 4096;                    \
    const ushort* vn = vS + (kt) * 64;                              \
    gld16(dK,               kn);                                    \
    gld16(dK + 2048,        kn + 2048);                             \
    gld16(dK + 4096,        vn);                                    \
    gld16(dK + 4096 + 2048, vn + (size_t)32 * 2048);                \
} while (0)

    int fo[4];
#pragma unroll
    for (int c = 0; c < 4; c++)
        fo[c] = l32 * 64 + ((((c << 1) | hi) ^ (l32 & 7)) << 3);

    const f32x16 Z16 = {0.f,0.f,0.f,0.f,0.f,0.f,0.f,0.f,0.f,0.f,0.f,0.f,0.f,0.f,0.f,0.f};
    f32x16 o0 = Z16, o1 = Z16;
    float m_run = -1e30f, l_run = 0.f;

    STG(0, 0);
    STG(1, 1);

    int cb = 0, nb = 2;
    for (int kt = 0; kt < S_ / 64; ++kt) {
        if (kt == S_ / 64 - 1) asm volatile("s_waitcnt vmcnt(0)" ::: "memory");
        else                   asm volatile("s_waitcnt vmcnt(4)" ::: "memory");
        __builtin_amdgcn_s_barrier();
        __builtin_amdgcn_sched_barrier(0);
        if (kt < S_ / 64 - 2) STG(nb, kt + 2);

        const ushort* KB = SM + cb * 8192;
        const ushort* VB = KB + 4096;

        f32x16 s0 = Z16, s1 = Z16;
        __builtin_amdgcn_s_setprio(1);
#pragma unroll
        for (int dc = 0; dc < 4; dc++) {
            s16x8 k0 = *(const s16x8*)(KB + fo[dc]);
            s16x8 k1 = *(const s16x8*)(KB + 2048 + fo[dc]);
            s0 = MFMA32(k0, qf[dc], s0);
            s1 = MFMA32(k1, qf[dc], s1);
        }
        __builtin_amdgcn_s_setprio(0);

        float m0 = fmaxf(s0[0], s1[0]), m1 = fmaxf(s0[1], s1[1]);
        float m2 = fmaxf(s0[2], s1[2]), m3 = fmaxf(s0[3], s1[3]);
#pragma unroll
        for (int r = 4; r < 16; r += 4) {
            m0 = fmaxf(m0, fmaxf(s0[r],     s1[r]));
            m1 = fmaxf(m1, fmaxf(s0[r + 1], s1[r + 1]));
            m2 = fmaxf(m2, fmaxf(s0[r + 2], s1[r + 2]));
            m3 = fmaxf(m3, fmaxf(s0[r + 3], s1[r + 3]));
        }
        float mx = fmaxf(fmaxf(m0, m1), fmaxf(m2, m3));
        mx = xmax32(mx);

        if (__any(mx > m_run + 8.f)) {
            float mnew = fmaxf(m_run, mx);
            float alpha = exp2_fast(m_run - mnew);
            m_run = mnew;
            l_run *= alpha;
#pragma unroll
            for (int r = 0; r < 16; r++) { o0[r] *= alpha; o1[r] *= alpha; }
        }

        float ra = 0.f, rb = 0.f;
#pragma unroll
        for (int r = 0; r < 16; r++) {
            s0[r] = exp2_fast(s0[r] - m_run); ra += s0[r];
            s1[r] = exp2_fast(s1[r] - m_run); rb += s1[r];
        }
        l_run += xadd32(ra + rb);

#pragma unroll
        for (int ks = 0; ks < 2; ks++) {
            const f32x16& p = ks ? s1 : s0;
            uint32_t u0 = cvtpk(p[0], p[1]),   u2 = cvtpk(p[4], p[5]);
            plswap(u0, u2);
            uint32_t u1 = cvtpk(p[2], p[3]),   u3 = cvtpk(p[6], p[7]);
            plswap(u1, u3);
            uint32_t w0 = cvtpk(p[8], p[9]),   w2 = cvtpk(p[12], p[13]);
            plswap(w0, w2);
            uint32_t w1 = cvtpk(p[10], p[11]), w3 = cvtpk(p[14], p[15]);
            plswap(w1, w3);
            union { uint32_t u[4]; s16x8 h; } F0, F1;
            F0.u[0] = u0; F0.u[1] = u1; F0.u[2] = u2; F0.u[3] = u3;
            F1.u[0] = w0; F1.u[1] = w1; F1.u[2] = w2; F1.u[3] = w3;

            const int kc0 = ks * 2, kc1 = ks * 2 + 1;
            s16x8 v00 = *(const s16x8*)(VB + fo[kc0]);
            s16x8 v01 = *(const s16x8*)(VB + 2048 + fo[kc0]);
            s16x8 v10 = *(const s16x8*)(VB + fo[kc1]);
            s16x8 v11 = *(const s16x8*)(VB + 2048 + fo[kc1]);
            __builtin_amdgcn_s_setprio(1);
            o0 = MFMA32(v00, F0.h, o0); o1 = MFMA32(v01, F0.h, o1);
            o0 = MFMA32(v10, F1.h, o0); o1 = MFMA32(v11, F1.h, o1);
            __builtin_amdgcn_s_setprio(0);
        }

        asm volatile("s_waitcnt lgkmcnt(0)" ::: "memory");
        cb = (cb == 2) ? 0 : cb + 1;
        nb = (nb == 2) ? 0 : nb + 1;
    }
#undef STG

    ushort* obuf = SM;  // [4][32][72]
    float inv = 1.0f / l_run;
    const int ob = (w * 32 + l32) * 72;
#pragma unroll
    for (int r = 0; r < 16; r++) {
        int d0 = (r & 3) + 8 * (r >> 2) + 4 * hi;
        obuf[ob + d0]      = f2bf(o0[r] * inv);
        obuf[ob + 32 + d0] = f2bf(o1[r] * inv);
    }
    asm volatile("s_waitcnt lgkmcnt(0)" ::: "memory");
    __builtin_amdgcn_sched_barrier(0);
    int b_ = bh >> 4, h = bh & 15;
    ushort* gp = ctx + ((size_t)(b_ * 2048 + q0 + l32)) * 1024 + h * 64 + hi * 32;
#pragma unroll
    for (int c = 0; c < 4; c++)
        *(s16x8*)(gp + c * 8) = *(const s16x8*)&obuf[ob + hi * 32 + c * 8];
}

extern "C" void kernel_launch(void* const* d_in, const int* in_sizes, int n_in,
                              void* d_out, int out_size, void* d_ws, size_t ws_size,
                              hipStream_t stream) {
    const float* X  = (const float*)d_in[0];
    const float* Wq = (const float*)d_in[1];
    const float* bq = (const float*)d_in[2];
    const float* Wk = (const float*)d_in[3];
    const float* bk = (const float*)d_in[4];
    const float* Wv = (const float*)d_in[5];
    const float* bv = (const float*)d_in[6];
    const float* Wo = (const float*)d_in[7];
    const float* bo = (const float*)d_in[8];
    float* out = (float*)d_out;

    // ws (MiB): wtq@0(2) wtk@2(2) wtv@4(2) wto@6(2) qws@8(8) kws@16(8)
    // ctx@24(8) = 32 MiB. d_out hosts V^T bf16 @0 (8 MiB) + Xbf16 @8MiB (8 MiB):
    // both dead before the final GEMM overwrites d_out.
    char* ws = (char*)d_ws;
    ushort* wtq  = (ushort*)(ws);
    ushort* wtk  = (ushort*)(ws + ((size_t)2 << 20));
    ushort* wtv  = (ushort*)(ws + ((size_t)4 << 20));
    ushort* wto  = (ushort*)(ws + ((size_t)6 << 20));
    ushort* qws  = (ushort*)(ws + ((size_t)8 << 20));
    ushort* kws  = (ushort*)(ws + ((size_t)16 << 20));
    ushort* ctx  = (ushort*)(ws + ((size_t)24 << 20));
    ushort* vtws = (ushort*)d_out;
    ushort* xbf  = (ushort*)d_out + ((size_t)4 << 20);  // +8 MiB

    // fused prep: 4 transposes + X cast in one launch
    prep<<<dim3(32, 32, 6), dim3(32, 8), 0, stream>>>(Wq, Wk, Wv, Wo, X,
                                                      wtq, wtk, wtv, wto, xbf);

    // fused QKV projection (modes 1/2/3)
    gemm_bt<<<dim3(8, 32, 3), 256, 0, stream>>>(xbf, wtq, wtk, wtv, bq, bk, bv,
                                                qws, kws, vtws, 1);

    attn<<<dim3(512), 256, 0, stream>>>(qws, kws, vtws, ctx);

    // output projection (mode 0)
    gemm_bt<<<dim3(8, 32, 1), 256, 0, stream>>>(ctx, wto, wto, wto, bo, bo, bo,
                                                out, out, out, 0);
}